// Round 11
// baseline (48.370 us; speedup 1.0000x reference)
//
#include <hip/hip_runtime.h>

// Scatter-as-matmul virial with BLOCK-SHARED one-hot matrix (R11).
// R10 post-mortem: per-wave-private M (11.5KB/wave) capped occupancy at
// ~12 waves/CU; DS-pipe ~43% busy, TA ~31%, nothing overlapped -> 44us.
// R11: one M[64][128] + Dt[16][128] per BLOCK (21.8KB -> 7 blocks/CU,
// 28 waves/CU). Threads 0..127 own one M column each (scattered plain
// writes, race-free); each of the 4 waves MFMAs only its 16-graph tile
// (K=128, 4x mfma_f32_16x16x32_bf16, single f32x4 acc). 2 barriers/group.
// Fragment layout/roles identical to R7/R8-verified code (A=M, B=Dt^T).

#define NG 64
#define NCOMP 6
#define NPART (NG * NCOMP)      // 384
#define RED1_BLOCKS 64
#define MFMA_BLOCKS 1792        // 7 blocks/CU
#define GE 128                  // edges per group (block-shared)
#define MROW 136                // 128 + 8 pad ushorts; 272B rows (16B-aligned)
#define DROW 136

typedef unsigned short u16_t;
typedef unsigned int   u32_t;
typedef __attribute__((ext_vector_type(8))) short short8;
typedef __attribute__((ext_vector_type(4))) float f32x4;

__device__ __forceinline__ u16_t f2bf(float f) {
    union { float f; u32_t u; } v; v.f = f;
    u32_t r = v.u + 0x7FFFu + ((v.u >> 16) & 1u);
    return (u16_t)(r >> 16);
}

__device__ __forceinline__ void lds_add(float* p, float v) {
    __hip_atomic_fetch_add(p, v, __ATOMIC_RELAXED, __HIP_MEMORY_SCOPE_WORKGROUP);
}

// ---------------- MFMA main kernel (block-shared M) ----------------
__global__ __launch_bounds__(256) void virial_mfma(
    const float* __restrict__ disp, const float* __restrict__ edge_w,
    const int* __restrict__ edge_index, const int* __restrict__ batch,
    float* __restrict__ partials, int E)
{
    __shared__ u16_t M [NG * MROW];   // 17408 B  (shared by whole block)
    __shared__ u16_t Dt[16 * DROW];   //  4352 B  (rows 6..15 stay zero;
                                      //  reused as f32 Osh[384] after loop)

    const int t    = threadIdx.x;
    const int lane = t & 63;
    const int wave = t >> 6;
    const int c_l  = lane & 15;
    const int k4   = lane >> 4;

    {   // cooperative zero of M and Dt
        u32_t* p = (u32_t*)M;
        for (int i = t; i < NG * MROW / 2; i += 256) p[i] = 0u;
        u32_t* q = (u32_t*)Dt;
        for (int i = t; i < 16 * DROW / 2; i += 256) q[i] = 0u;
    }
    __syncthreads();

    f32x4 acc = {0.f, 0.f, 0.f, 0.f};
    const int  ngroups = (E + GE - 1) / GE;
    const int  gstride = (int)gridDim.x;
    const bool loader  = (t < GE);

    int grp = (int)blockIdx.x;
    int pg0 = 0, pg1 = 0;

    // 1-deep prefetch of this group's load chain (threads 0..127)
    int   p_g0 = 0, p_g1 = 0;
    float p_w = 0.f, p_d0 = 0.f, p_d1 = 0.f, p_d2 = 0.f;
    if (loader && grp < ngroups) {
        int e  = grp * GE + t;
        int ec = e < E ? e : E - 1;
        p_w  = (e < E) ? edge_w[ec] : 0.f;      // w=0 kills clamped-tail terms
        p_d0 = disp[ec * 3 + 0];
        p_d1 = disp[ec * 3 + 1];
        p_d2 = disp[ec * 3 + 2];
        p_g0 = batch[edge_index[ec]];
        p_g1 = batch[edge_index[E + ec]];
    }

    while (grp < ngroups) {
        const int   g0 = p_g0, g1 = p_g1;
        const float w = p_w, d0 = p_d0, d1 = p_d1, d2 = p_d2;
        const int   nxt = grp + gstride;

        __syncthreads();              // all frag reads of prev group done
        if (loader) {
            // one-hot column t (plain stores, race-free; zero stale rows)
            M[pg0 * MROW + t] = 0;
            M[pg1 * MROW + t] = 0;
            M[g0 * MROW + t] = 0x3F80u;                          // 1.0
            M[g1 * MROW + t] = (g1 == g0) ? 0x4000u : 0x3F80u;   // 2.0 / 1.0
            pg0 = g0; pg1 = g1;

            float cw = -2.f * w;
            Dt[0 * DROW + t] = f2bf(cw * d0 * d0);
            Dt[1 * DROW + t] = f2bf(cw * d0 * d1);
            Dt[2 * DROW + t] = f2bf(cw * d0 * d2);
            Dt[3 * DROW + t] = f2bf(cw * d1 * d1);
            Dt[4 * DROW + t] = f2bf(cw * d1 * d2);
            Dt[5 * DROW + t] = f2bf(cw * d2 * d2);
        }
        __syncthreads();              // M/Dt ready for all waves

        // prefetch next group's chain; overlaps the MFMA phase below
        if (loader && nxt < ngroups) {
            int e  = nxt * GE + t;
            int ec = e < E ? e : E - 1;
            p_w  = (e < E) ? edge_w[ec] : 0.f;
            p_d0 = disp[ec * 3 + 0];
            p_d1 = disp[ec * 3 + 1];
            p_d2 = disp[ec * 3 + 2];
            p_g0 = batch[edge_index[ec]];
            p_g1 = batch[edge_index[E + ec]];
        }

        // wave computes ONLY its 16-graph tile: rows 16*wave .. 16*wave+15
#pragma unroll
        for (int q = 0; q < 4; ++q) {
            const int kb = q * 32 + k4 * 8;
            short8 bf = *(const short8*)&Dt[c_l * DROW + kb];
            short8 af = *(const short8*)&M[(16 * wave + c_l) * MROW + kb];
            acc = __builtin_amdgcn_mfma_f32_16x16x32_bf16(af, bf, acc, 0, 0, 0);
        }

        grp = nxt;
    }

    __syncthreads();                  // all waves done reading Dt
    // C/D layout: col=lane&15 (component), row=(lane>>4)*4+reg (graph-in-tile)
    float* Osh = (float*)Dt;          // 1536 B needed <= 4352 B
    if (c_l < NCOMP) {
#pragma unroll
        for (int r = 0; r < 4; ++r)
            Osh[(16 * wave + k4 * 4 + r) * NCOMP + c_l] = acc[r];
    }
    __syncthreads();
    for (int i = t; i < NPART; i += 256)
        partials[(size_t)blockIdx.x * NPART + i] = Osh[i];
}

// ---------------- reductions (atomic-free) ----------------
__global__ __launch_bounds__(NPART) void reduce1_kernel(
    const float* __restrict__ partials, float* __restrict__ partials2, int nblk)
{
    int i = threadIdx.x, j = blockIdx.x;
    float s = 0.f;
    for (int b = j; b < nblk; b += RED1_BLOCKS)
        s += partials[(size_t)b * NPART + i];
    partials2[(size_t)j * NPART + i] = s;
}

__global__ __launch_bounds__(NPART) void reduce2_kernel(
    const float* __restrict__ partials2, float* __restrict__ dst)  // dst: 64*9
{
    int i = threadIdx.x;
    float s = 0.f;
#pragma unroll
    for (int j = 0; j < RED1_BLOCKS; ++j)
        s += partials2[(size_t)j * NPART + i];
    int g = i / NCOMP, c = i % NCOMP;
    int r   = (c < 3) ? 0 : ((c < 5) ? 1 : 2);
    int col = (c < 3) ? c : ((c < 5) ? c - 2 : 2);
    dst[g * 9 + r * 3 + col] = s;
    if (r != col) dst[g * 9 + col * 3 + r] = s;
}

// ---------------- fallback (tiny ws): LDS-atomic path ----------------
__global__ void zero_out_kernel(float* __restrict__ out, int n) {
    int i = blockIdx.x * blockDim.x + threadIdx.x;
    if (i < n) out[i] = 0.f;
}

__global__ __launch_bounds__(256) void virial_atomic(
    const float* __restrict__ disp, const float* __restrict__ edge_w,
    const int* __restrict__ edge_index, const int* __restrict__ batch,
    float* __restrict__ out, int E)
{
    __shared__ float acc[NG * 7];
    for (int i = threadIdx.x; i < NG * 7; i += blockDim.x) acc[i] = 0.f;
    __syncthreads();
    int tid = blockIdx.x * blockDim.x + threadIdx.x;
    int stride = gridDim.x * blockDim.x;
    for (int e = tid; e < E; e += stride) {
        float d0 = disp[e*3], d1 = disp[e*3+1], d2 = disp[e*3+2];
        float c = -2.f * edge_w[e];
        int g0 = batch[edge_index[e]], g1 = batch[edge_index[E + e]];
        float v[6] = {c*d0*d0, c*d0*d1, c*d0*d2, c*d1*d1, c*d1*d2, c*d2*d2};
#pragma unroll
        for (int k = 0; k < 6; ++k) {
            lds_add(&acc[g0*7+k], v[k]);
            lds_add(&acc[g1*7+k], v[k]);
        }
    }
    __syncthreads();
    for (int i = threadIdx.x; i < NG * 9; i += blockDim.x) {
        int g = i / 9, ij = i % 9, r = ij / 3, cc = ij % 3;
        int lo = r < cc ? r : cc, hi = r < cc ? cc : r;
        int comp = (lo == 0) ? hi : ((lo == 1) ? 2 + hi : 5);
        __hip_atomic_fetch_add(&out[i], acc[g*7+comp], __ATOMIC_RELAXED, __HIP_MEMORY_SCOPE_AGENT);
    }
}

extern "C" void kernel_launch(void* const* d_in, const int* in_sizes, int n_in,
                              void* d_out, int out_size, void* d_ws, size_t ws_size,
                              hipStream_t stream) {
    const float* disp       = (const float*)d_in[0];
    const float* edge_w     = (const float*)d_in[1];
    const int*   edge_index = (const int*)d_in[2];
    const int*   batch      = (const int*)d_in[3];
    float*       out        = (float*)d_out;
    const int E = in_sizes[1];

    // Cap grid at the group count (grid-stride handles the rest).
    int ngroups = (E + GE - 1) / GE;
    int nblk = MFMA_BLOCKS < ngroups ? MFMA_BLOCKS : ngroups;

    const size_t need = (size_t)(nblk + RED1_BLOCKS) * NPART * sizeof(float);

    if (ws_size >= need) {
        float* pm = (float*)d_ws;                      // [nblk][NPART]
        float* p2 = pm + (size_t)nblk * NPART;         // [RED1_BLOCKS][NPART]

        virial_mfma<<<nblk, 256, 0, stream>>>(disp, edge_w, edge_index, batch, pm, E);
        reduce1_kernel<<<RED1_BLOCKS, NPART, 0, stream>>>(pm, p2, nblk);
        reduce2_kernel<<<1, NPART, 0, stream>>>(p2, out);
    } else {
        zero_out_kernel<<<1, 256, 0, stream>>>(out, NG * 9);
        virial_atomic<<<2048, 256, 0, stream>>>(disp, edge_w, edge_index, batch, out, E);
    }
}